// Round 7
// baseline (961.457 us; speedup 1.0000x reference)
//
#include <hip/hip_runtime.h>
#include <hip/hip_fp16.h>
#include <math.h>

#define IN_CH 8
#define HID   64
#define EMB   32
#define SCAN_T 4096     // 16 blocks x 256 for the histogram scan
#define HBLK  256       // blocks in hist/scatter phases
#define BW    128       // nodes per bucket (dst >> 7)
#define NBMAX 800       // max buckets supported (N <= 102400)

static __device__ __forceinline__ __half2 u2h2(unsigned u) {
    union { unsigned u; __half2 h; } c; c.u = u; return c.h;
}
static __device__ __forceinline__ unsigned h22u(__half2 h) {
    union { unsigned u; __half2 h; } c; c.h = h; return c.u;
}

// ------------------------------------------------- pass A1: per-block bucket histogram
__global__ __launch_bounds__(256) void hist_kernel(const int* __restrict__ ei,
                                                   int* __restrict__ hist2, int E, int NB) {
    __shared__ int lh[NBMAX];
    int b = blockIdx.x, t = threadIdx.x;
    for (int i = t; i < NB; i += 256) lh[i] = 0;
    __syncthreads();
    int per = (E + gridDim.x - 1) / gridDim.x;
    int e0 = b * per, e1 = min(e0 + per, E);
    for (int e = e0 + t; e < e1; e += 256)
        atomicAdd(&lh[ei[E + e] >> 7], 1);
    __syncthreads();
    for (int i = t; i < NB; i += 256) hist2[b * NB + i] = lh[i];
}

// ------------------------------------------------- hist scan (bucket-major logical order)
// logical l = bucket*HBLK + block ; phys = block*NB + bucket
__global__ void hscanA_kernel(const int* __restrict__ hist2, int* __restrict__ tsum,
                              int M, int NB) {
    int tid = blockIdx.x * blockDim.x + threadIdx.x;
    int chunk = (M + SCAN_T - 1) / SCAN_T;
    int start = tid * chunk, end = min(start + chunk, M);
    int s = 0;
    for (int l = start; l < end; l++) s += hist2[(l & (HBLK - 1)) * NB + (l >> 8)];
    tsum[tid] = s;
}

__global__ __launch_bounds__(256) void hscanB_kernel(const int* __restrict__ tsum,
                                                     int* __restrict__ tpre) {
    __shared__ int bsum[256];
    int t = threadIdx.x;
    int s = 0;
    #pragma unroll
    for (int i = 0; i < 16; i++) s += tsum[t * 16 + i];
    bsum[t] = s;
    __syncthreads();
    for (int off = 1; off < 256; off <<= 1) {
        int v = (t >= off) ? bsum[t - off] : 0;
        __syncthreads();
        bsum[t] += v;
        __syncthreads();
    }
    int run = (t == 0) ? 0 : bsum[t - 1];
    #pragma unroll
    for (int i = 0; i < 16; i++) { tpre[t * 16 + i] = run; run += tsum[t * 16 + i]; }
}

__global__ void hscanC_kernel(const int* __restrict__ hist2, const int* __restrict__ tpre,
                              int* __restrict__ off2, int M, int NB) {
    int tid = blockIdx.x * blockDim.x + threadIdx.x;
    int chunk = (M + SCAN_T - 1) / SCAN_T;
    int start = tid * chunk, end = min(start + chunk, M);
    int run = tpre[tid];
    for (int l = start; l < end; l++) {
        int ph = (l & (HBLK - 1)) * NB + (l >> 8);
        off2[ph] = run;
        run += hist2[ph];
    }
}

// ------------------------------------------------- pass A2: scatter edges (packed src|li)
__global__ __launch_bounds__(256) void scat_kernel(const int* __restrict__ ei,
                                                   const int* __restrict__ off2,
                                                   int* __restrict__ staged, int E, int NB) {
    __shared__ int lcur[NBMAX];
    int b = blockIdx.x, t = threadIdx.x;
    for (int i = t; i < NB; i += 256) lcur[i] = off2[b * NB + i];
    __syncthreads();
    int per = (E + gridDim.x - 1) / gridDim.x;
    int e0 = b * per, e1 = min(e0 + per, E);
    for (int e = e0 + t; e < e1; e += 256) {
        int src = ei[e], dst = ei[E + e];
        int pos = atomicAdd(&lcur[dst >> 7], 1);
        staged[pos] = src | ((dst & (BW - 1)) << 17);   // src<2^17, li<128
    }
}

// ------------------------------------------------- bagg1: bucket-wise layer-1 aggregate
// + fused dense1 + dense2-precompute.
// Block per bucket: LDS-accumulate x[src] sums + degree over the bucket's staged
// edge segment (contiguous), then per-node dense chain (2 threads/node):
// h = relu(mean@W1l + b1 + x@W1r); p = h@W2l (fp16); self = h@W2r + b2 (fp32).
__global__ __launch_bounds__(256) void bagg1_kernel(
        const float* __restrict__ x, const int* __restrict__ staged,
        const int* __restrict__ off2,
        const float* __restrict__ W1l, const float* __restrict__ b1,
        const float* __restrict__ W1r,
        const float* __restrict__ W2l, const float* __restrict__ b2,
        const float* __restrict__ W2r,
        unsigned* __restrict__ p16, float* __restrict__ selfb,
        int* __restrict__ degb, int N, int E, int NB) {
    __shared__ float xs[BW * 9];    // pad 9 to break bank alignment
    __shared__ int ideg[BW];
    int b = blockIdx.x, t = threadIdx.x;
    int base = b * BW;
    int s0 = off2[b];
    int s1 = (b + 1 < NB) ? off2[b + 1] : E;

    for (int i = t; i < BW * 9; i += 256) xs[i] = 0.0f;
    if (t < BW) ideg[t] = 0;
    __syncthreads();

    int g = t >> 3;      // 32 edge-groups
    int c = t & 7;       // channel
    for (int e = s0 + g; e < s1; e += 128) {           // unroll 4 (stride 32)
        int v0 = staged[e];
        int v1 = (e + 32 < s1) ? staged[e + 32] : -1;
        int v2 = (e + 64 < s1) ? staged[e + 64] : -1;
        int v3 = (e + 96 < s1) ? staged[e + 96] : -1;
        float x0 = x[(size_t)(v0 & 0x1FFFF) * IN_CH + c];
        float x1 = (v1 >= 0) ? x[(size_t)(v1 & 0x1FFFF) * IN_CH + c] : 0.0f;
        float x2 = (v2 >= 0) ? x[(size_t)(v2 & 0x1FFFF) * IN_CH + c] : 0.0f;
        float x3 = (v3 >= 0) ? x[(size_t)(v3 & 0x1FFFF) * IN_CH + c] : 0.0f;
        atomicAdd(&xs[(v0 >> 17) * 9 + c], x0);
        if (c == 0) atomicAdd(&ideg[v0 >> 17], 1);
        if (v1 >= 0) { atomicAdd(&xs[(v1 >> 17) * 9 + c], x1);
                       if (c == 0) atomicAdd(&ideg[v1 >> 17], 1); }
        if (v2 >= 0) { atomicAdd(&xs[(v2 >> 17) * 9 + c], x2);
                       if (c == 0) atomicAdd(&ideg[v2 >> 17], 1); }
        if (v3 >= 0) { atomicAdd(&xs[(v3 >> 17) * 9 + c], x3);
                       if (c == 0) atomicAdd(&ideg[v3 >> 17], 1); }
    }
    __syncthreads();

    // dense phase: threads 0..127 = half 0 (j 0..15), 128..255 = half 1 (j 16..31)
    int half = t >> 7;
    int li = t & 127;
    int node = base + li;
    if (node >= N) return;

    float dg = (float)ideg[li];
    float inv = 1.0f / fmaxf(dg, 1.0f);
    float av[IN_CH], xv[IN_CH];
    #pragma unroll
    for (int cc = 0; cc < IN_CH; cc++) av[cc] = xs[li * 9 + cc] * inv;
    {
        float4 a0 = ((const float4*)(x + (size_t)node * IN_CH))[0];
        float4 a1 = ((const float4*)(x + (size_t)node * IN_CH))[1];
        xv[0] = a0.x; xv[1] = a0.y; xv[2] = a0.z; xv[3] = a0.w;
        xv[4] = a1.x; xv[5] = a1.y; xv[6] = a1.z; xv[7] = a1.w;
    }

    float pacc[16], sacc[16];
    const float* W2lh = W2l + half * 16;
    const float* W2rh = W2r + half * 16;
    #pragma unroll
    for (int j = 0; j < 16; j++) { pacc[j] = 0.0f; sacc[j] = b2[half * 16 + j]; }

    for (int k = 0; k < HID; k++) {
        float hk = b1[k];
        #pragma unroll
        for (int cc = 0; cc < IN_CH; cc++)
            hk += av[cc] * W1l[cc * HID + k] + xv[cc] * W1r[cc * HID + k];
        hk = fmaxf(hk, 0.0f);
        #pragma unroll
        for (int j = 0; j < 16; j++) {
            pacc[j] += hk * W2lh[k * EMB + j];
            sacc[j] += hk * W2rh[k * EMB + j];
        }
    }

    unsigned up[8];
    #pragma unroll
    for (int m = 0; m < 8; m++)
        up[m] = h22u(__floats2half2_rn(pacc[2 * m], pacc[2 * m + 1]));
    uint4* pp = (uint4*)(p16 + (size_t)node * 16 + half * 8);
    pp[0] = make_uint4(up[0], up[1], up[2], up[3]);
    pp[1] = make_uint4(up[4], up[5], up[6], up[7]);
    float4* sp = (float4*)(selfb + (size_t)node * EMB + half * 16);
    #pragma unroll
    for (int m = 0; m < 4; m++)
        sp[m] = make_float4(sacc[4 * m], sacc[4 * m + 1], sacc[4 * m + 2], sacc[4 * m + 3]);
    if (half == 0) degb[node] = ideg[li];
}

// ------------------------------------------------- bagg2: bucket-wise layer-2 aggregate + head
// Block per bucket: LDS-accumulate p[src] (fp16 rows, fp32 LDS accum) over the
// bucket's staged segment with deep unroll (8 loads in flight/lane), then
// thread-per-node mean+self+relu + head MLP + sigmoid.
__global__ __launch_bounds__(256) void bagg2_kernel(
        const unsigned* __restrict__ p16, const float* __restrict__ selfb,
        const int* __restrict__ degb,
        const int* __restrict__ staged, const int* __restrict__ off2,
        const float* __restrict__ Wh1, const float* __restrict__ bh1,
        const float* __restrict__ Wh2, const float* __restrict__ bh2,
        float* __restrict__ out, int N, int E, int NB) {
    __shared__ float zs[BW * 33];   // pad 33: head reads conflict-free, adds ~4-way max
    int b = blockIdx.x, t = threadIdx.x;
    int base = b * BW;
    int s0 = off2[b];
    int s1 = (b + 1 < NB) ? off2[b + 1] : E;

    for (int i = t; i < BW * 33; i += 256) zs[i] = 0.0f;
    __syncthreads();

    int g = t >> 4;      // 16 edge-groups
    int c4 = t & 15;     // dword (channel pair) within 64B p row
    for (int e = s0 + g; e < s1; e += 64) {            // unroll 4 (stride 16)
        int v0 = staged[e];
        int v1 = (e + 16 < s1) ? staged[e + 16] : -1;
        int v2 = (e + 32 < s1) ? staged[e + 32] : -1;
        int v3 = (e + 48 < s1) ? staged[e + 48] : -1;
        unsigned u0 = p16[(size_t)(v0 & 0x1FFFF) * 16 + c4];
        unsigned u1 = (v1 >= 0) ? p16[(size_t)(v1 & 0x1FFFF) * 16 + c4] : 0u;
        unsigned u2 = (v2 >= 0) ? p16[(size_t)(v2 & 0x1FFFF) * 16 + c4] : 0u;
        unsigned u3 = (v3 >= 0) ? p16[(size_t)(v3 & 0x1FFFF) * 16 + c4] : 0u;
        float2 f0 = __half22float2(u2h2(u0));
        atomicAdd(&zs[(v0 >> 17) * 33 + 2 * c4], f0.x);
        atomicAdd(&zs[(v0 >> 17) * 33 + 2 * c4 + 1], f0.y);
        if (v1 >= 0) { float2 f = __half22float2(u2h2(u1));
                       atomicAdd(&zs[(v1 >> 17) * 33 + 2 * c4], f.x);
                       atomicAdd(&zs[(v1 >> 17) * 33 + 2 * c4 + 1], f.y); }
        if (v2 >= 0) { float2 f = __half22float2(u2h2(u2));
                       atomicAdd(&zs[(v2 >> 17) * 33 + 2 * c4], f.x);
                       atomicAdd(&zs[(v2 >> 17) * 33 + 2 * c4 + 1], f.y); }
        if (v3 >= 0) { float2 f = __half22float2(u2h2(u3));
                       atomicAdd(&zs[(v3 >> 17) * 33 + 2 * c4], f.x);
                       atomicAdd(&zs[(v3 >> 17) * 33 + 2 * c4 + 1], f.y); }
    }
    __syncthreads();

    if (t >= BW) return;
    int node = base + t;
    if (node >= N) return;

    float inv = 1.0f / fmaxf((float)degb[node], 1.0f);
    float z[EMB];
    const float4* sb = (const float4*)(selfb + (size_t)node * EMB);
    #pragma unroll
    for (int m = 0; m < 8; m++) {
        float4 s4 = sb[m];
        z[4 * m + 0] = fmaxf(zs[t * 33 + 4 * m + 0] * inv + s4.x, 0.0f);
        z[4 * m + 1] = fmaxf(zs[t * 33 + 4 * m + 1] * inv + s4.y, 0.0f);
        z[4 * m + 2] = fmaxf(zs[t * 33 + 4 * m + 2] * inv + s4.z, 0.0f);
        z[4 * m + 3] = fmaxf(zs[t * 33 + 4 * m + 3] * inv + s4.w, 0.0f);
    }

    float logit = bh2[0];
    #pragma unroll
    for (int i = 0; i < 16; i++) {
        float acc = bh1[i];
        #pragma unroll
        for (int k = 0; k < EMB; k++) acc += z[k] * Wh1[k * 16 + i];
        logit += fmaxf(acc, 0.0f) * Wh2[i];
    }
    out[node] = 1.0f / (1.0f + expf(-logit));
}

// ---------------------------------------------------------------- launch
extern "C" void kernel_launch(void* const* d_in, const int* in_sizes, int n_in,
                              void* d_out, int out_size, void* d_ws, size_t ws_size,
                              hipStream_t stream) {
    const float* x   = (const float*)d_in[0];
    const int*   ei  = (const int*)d_in[1];
    const float* W1l = (const float*)d_in[2];
    const float* b1  = (const float*)d_in[3];
    const float* W1r = (const float*)d_in[4];
    const float* W2l = (const float*)d_in[5];
    const float* b2  = (const float*)d_in[6];
    const float* W2r = (const float*)d_in[7];
    const float* Wh1 = (const float*)d_in[8];
    const float* bh1 = (const float*)d_in[9];
    const float* Wh2 = (const float*)d_in[10];
    const float* bh2 = (const float*)d_in[11];

    int N = in_sizes[0] / IN_CH;     // 100000
    int E = in_sizes[1] / 2;         // 3200000
    int NB = (N + BW - 1) / BW;      // 782 buckets
    int M  = NB * HBLK;              // histogram cells

    // workspace layout:
    // [staged int E][hist2 M][off2 M][tsum 4096][tpre 4096][degb N]
    // [p16 16N u32][selfb 32N f32]
    int* staged   = (int*)d_ws;
    int* hist2    = staged + E;
    int* off2     = hist2 + M;
    int* tsum     = off2 + M;
    int* tpre     = tsum + SCAN_T;
    int* degb     = tpre + SCAN_T;
    unsigned* p16 = (unsigned*)(degb + N);
    float* selfb  = (float*)(p16 + (size_t)N * 16);

    hist_kernel  <<<HBLK, 256, 0, stream>>>(ei, hist2, E, NB);
    hscanA_kernel<<<SCAN_T / 256, 256, 0, stream>>>(hist2, tsum, M, NB);
    hscanB_kernel<<<1, 256, 0, stream>>>(tsum, tpre);
    hscanC_kernel<<<SCAN_T / 256, 256, 0, stream>>>(hist2, tpre, off2, M, NB);
    scat_kernel  <<<HBLK, 256, 0, stream>>>(ei, off2, staged, E, NB);
    bagg1_kernel <<<NB, 256, 0, stream>>>(x, staged, off2, W1l, b1, W1r,
                                          W2l, b2, W2r, p16, selfb, degb, N, E, NB);
    bagg2_kernel <<<NB, 256, 0, stream>>>(p16, selfb, degb, staged, off2,
                                          Wh1, bh1, Wh2, bh2, (float*)d_out, N, E, NB);
}

// Round 8
// 246.319 us; speedup vs baseline: 3.9033x; 3.9033x over previous
//
#include <hip/hip_runtime.h>
#include <hip/hip_fp16.h>
#include <math.h>

#define IN_CH 8
#define HID   64
#define EMB   32
#define SCAN_T 4096     // 16 blocks x 256 for the histogram scan
#define HBLK  256       // blocks in hist/scatter phases
#define BW    128       // nodes per bucket (dst >> 7)
#define NBMAX 800       // max buckets supported (N <= 102400)

static __device__ __forceinline__ __half2 u2h2(unsigned u) {
    union { unsigned u; __half2 h; } c; c.u = u; return c.h;
}
static __device__ __forceinline__ unsigned h22u(__half2 h) {
    union { unsigned u; __half2 h; } c; c.h = h; return c.u;
}

// ------------------------------------------------- pass A1: per-block bucket histogram
__global__ __launch_bounds__(256) void hist_kernel(const int* __restrict__ ei,
                                                   int* __restrict__ hist2, int E, int NB) {
    __shared__ int lh[NBMAX];
    int b = blockIdx.x, t = threadIdx.x;
    for (int i = t; i < NB; i += 256) lh[i] = 0;
    __syncthreads();
    int per = (E + gridDim.x - 1) / gridDim.x;
    int e0 = b * per, e1 = min(e0 + per, E);
    for (int e = e0 + t; e < e1; e += 256)
        atomicAdd(&lh[ei[E + e] >> 7], 1);
    __syncthreads();
    for (int i = t; i < NB; i += 256) hist2[b * NB + i] = lh[i];
}

// ------------------------------------------------- hist scan (bucket-major logical order)
// logical l = bucket*HBLK + block ; phys = block*NB + bucket
__global__ void hscanA_kernel(const int* __restrict__ hist2, int* __restrict__ tsum,
                              int M, int NB) {
    int tid = blockIdx.x * blockDim.x + threadIdx.x;
    int chunk = (M + SCAN_T - 1) / SCAN_T;
    int start = tid * chunk, end = min(start + chunk, M);
    int s = 0;
    for (int l = start; l < end; l++) s += hist2[(l & (HBLK - 1)) * NB + (l >> 8)];
    tsum[tid] = s;
}

__global__ __launch_bounds__(256) void hscanB_kernel(const int* __restrict__ tsum,
                                                     int* __restrict__ tpre) {
    __shared__ int bsum[256];
    int t = threadIdx.x;
    int s = 0;
    #pragma unroll
    for (int i = 0; i < 16; i++) s += tsum[t * 16 + i];
    bsum[t] = s;
    __syncthreads();
    for (int off = 1; off < 256; off <<= 1) {
        int v = (t >= off) ? bsum[t - off] : 0;
        __syncthreads();
        bsum[t] += v;
        __syncthreads();
    }
    int run = (t == 0) ? 0 : bsum[t - 1];
    #pragma unroll
    for (int i = 0; i < 16; i++) { tpre[t * 16 + i] = run; run += tsum[t * 16 + i]; }
}

__global__ void hscanC_kernel(const int* __restrict__ hist2, const int* __restrict__ tpre,
                              int* __restrict__ off2, int M, int NB) {
    int tid = blockIdx.x * blockDim.x + threadIdx.x;
    int chunk = (M + SCAN_T - 1) / SCAN_T;
    int start = tid * chunk, end = min(start + chunk, M);
    int run = tpre[tid];
    for (int l = start; l < end; l++) {
        int ph = (l & (HBLK - 1)) * NB + (l >> 8);
        off2[ph] = run;
        run += hist2[ph];
    }
}

// ------------------------------------------------- pass A2: scatter edges (packed src|li)
__global__ __launch_bounds__(256) void scat_kernel(const int* __restrict__ ei,
                                                   const int* __restrict__ off2,
                                                   int* __restrict__ staged, int E, int NB) {
    __shared__ int lcur[NBMAX];
    int b = blockIdx.x, t = threadIdx.x;
    for (int i = t; i < NB; i += 256) lcur[i] = off2[b * NB + i];
    __syncthreads();
    int per = (E + gridDim.x - 1) / gridDim.x;
    int e0 = b * per, e1 = min(e0 + per, E);
    for (int e = e0 + t; e < e1; e += 256) {
        int src = ei[e], dst = ei[E + e];
        int pos = atomicAdd(&lcur[dst >> 7], 1);
        staged[pos] = src | ((dst & (BW - 1)) << 17);   // src<2^17, li<128
    }
}

// ------------------------------------------------- pass B: per-bucket CSR build
__global__ __launch_bounds__(256) void bucket_kernel(const int* __restrict__ staged,
                                                     const int* __restrict__ off2,
                                                     int* __restrict__ row_off,
                                                     int* __restrict__ csr,
                                                     int N, int E, int NB) {
    __shared__ int cnt[BW], offx[BW], cur[BW];
    int b = blockIdx.x, t = threadIdx.x;
    int base = b * BW;
    int s0 = off2[b];
    int s1 = (b + 1 < NB) ? off2[b + 1] : E;
    if (t < BW) cnt[t] = 0;
    __syncthreads();
    for (int e = s0 + t; e < s1; e += 256)
        atomicAdd(&cnt[staged[e] >> 17], 1);
    __syncthreads();
    if (t < BW) offx[t] = cnt[t];
    __syncthreads();
    for (int off = 1; off < BW; off <<= 1) {
        int v = (t >= off && t < BW) ? offx[t - off] : 0;
        __syncthreads();
        if (t < BW) offx[t] += v;
        __syncthreads();
    }
    if (t < BW) {
        int ex = offx[t] - cnt[t];
        if (base + t < N) row_off[base + t] = s0 + ex;
        cnt[t] = ex;
        cur[t] = 0;
    }
    if (b == NB - 1 && t == 0) row_off[N] = s1;
    __syncthreads();
    for (int e = s0 + t; e < s1; e += 256) {
        int v = staged[e];
        int li = v >> 17;
        int pos = s0 + cnt[li] + atomicAdd(&cur[li], 1);
        csr[pos] = v & 0x1FFFF;
    }
}

// ------------------------------------------------- gather1: mean of x, 4 lanes per node
// lane q owns channels 2q,2q+1 (float2). 16 independent node streams per wave.
__global__ __launch_bounds__(256) void gather1_kernel(
        const float* __restrict__ x, const int* __restrict__ row_off,
        const int* __restrict__ csr, float* __restrict__ aggr, int N) {
    int t = threadIdx.x;
    int node = blockIdx.x * 64 + (t >> 2);
    int q = t & 3;
    if (node >= N) return;
    int r0 = row_off[node], r1 = row_off[node + 1];
    int deg = r1 - r0;

    float ax = 0.0f, ay = 0.0f;
    int e = r0;
    for (; e + 2 <= r1; e += 2) {
        int i0 = csr[e], i1 = csr[e + 1];
        float2 v0 = *(const float2*)(x + (size_t)i0 * IN_CH + q * 2);
        float2 v1 = *(const float2*)(x + (size_t)i1 * IN_CH + q * 2);
        ax += v0.x + v1.x; ay += v0.y + v1.y;
    }
    if (e < r1) {
        float2 v0 = *(const float2*)(x + (size_t)csr[e] * IN_CH + q * 2);
        ax += v0.x; ay += v0.y;
    }
    float inv = 1.0f / fmaxf((float)deg, 1.0f);
    // full x-row mean split across 4 lanes? lane q holds ch 2q..2q+1 only -> need
    // the other half: lanes cover 8 channels via q*2 and q*2+... store float2:
    ((float2*)(aggr + (size_t)node * IN_CH))[q] = make_float2(ax * inv, ay * inv);
}

// ------------------------------------------------- dense1b: node-per-thread dense chain
// h = relu(aggr@W1l + b1 + x@W1r); p16 = h@W2l (fp16, 64B row); self = h@W2r + b2.
__global__ __launch_bounds__(128) void dense1b_kernel(
        const float* __restrict__ x, const float* __restrict__ aggr,
        const float* __restrict__ W1l, const float* __restrict__ b1,
        const float* __restrict__ W1r,
        const float* __restrict__ W2l, const float* __restrict__ b2,
        const float* __restrict__ W2r,
        unsigned* __restrict__ p16, float* __restrict__ selfb, int N) {
    int n = blockIdx.x * 128 + threadIdx.x;
    if (n >= N) return;

    float av[IN_CH], xv[IN_CH];
    {
        float4 a0 = ((const float4*)(aggr + (size_t)n * IN_CH))[0];
        float4 a1 = ((const float4*)(aggr + (size_t)n * IN_CH))[1];
        av[0] = a0.x; av[1] = a0.y; av[2] = a0.z; av[3] = a0.w;
        av[4] = a1.x; av[5] = a1.y; av[6] = a1.z; av[7] = a1.w;
        float4 b0 = ((const float4*)(x + (size_t)n * IN_CH))[0];
        float4 b1v = ((const float4*)(x + (size_t)n * IN_CH))[1];
        xv[0] = b0.x; xv[1] = b0.y; xv[2] = b0.z; xv[3] = b0.w;
        xv[4] = b1v.x; xv[5] = b1v.y; xv[6] = b1v.z; xv[7] = b1v.w;
    }

    float pacc[EMB], sacc[EMB];
    #pragma unroll
    for (int j = 0; j < EMB; j++) { pacc[j] = 0.0f; sacc[j] = b2[j]; }

    for (int k = 0; k < HID; k++) {
        float hk = b1[k];
        #pragma unroll
        for (int c = 0; c < IN_CH; c++)
            hk += av[c] * W1l[c * HID + k] + xv[c] * W1r[c * HID + k];
        hk = fmaxf(hk, 0.0f);
        const float* wl = W2l + k * EMB;
        const float* wr = W2r + k * EMB;
        #pragma unroll
        for (int j = 0; j < EMB; j++) {
            pacc[j] += hk * wl[j];
            sacc[j] += hk * wr[j];
        }
    }

    unsigned up[16];
    #pragma unroll
    for (int m = 0; m < 16; m++)
        up[m] = h22u(__floats2half2_rn(pacc[2 * m], pacc[2 * m + 1]));
    uint4* pp = (uint4*)(p16 + (size_t)n * 16);
    pp[0] = make_uint4(up[0], up[1], up[2], up[3]);
    pp[1] = make_uint4(up[4], up[5], up[6], up[7]);
    pp[2] = make_uint4(up[8], up[9], up[10], up[11]);
    pp[3] = make_uint4(up[12], up[13], up[14], up[15]);
    float4* sp = (float4*)(selfb + (size_t)n * EMB);
    #pragma unroll
    for (int m = 0; m < 8; m++)
        sp[m] = make_float4(sacc[4 * m], sacc[4 * m + 1], sacc[4 * m + 2], sacc[4 * m + 3]);
}

// ------------------------------------------------- gather2: 4 lanes per node + head
// lane q owns channels 8q..8q+7 (one uint4 of the 64B fp16 p-row). Packed fp16
// accumulate, no shfl, 16 independent node streams per wave. Phase 2: thread-
// per-node head MLP through padded LDS.
__global__ __launch_bounds__(256) void gather2_kernel(
        const unsigned* __restrict__ p16, const float* __restrict__ selfb,
        const int* __restrict__ row_off, const int* __restrict__ csr,
        const float* __restrict__ Wh1, const float* __restrict__ bh1,
        const float* __restrict__ Wh2, const float* __restrict__ bh2,
        float* __restrict__ out, int N) {
    __shared__ float zs[64 * 34];     // pitch 34: 2-way max on writes, free
    __shared__ float sW1[EMB * 16];
    __shared__ float sbh1[16];
    __shared__ float sW2[16];
    __shared__ float sbh2;
    int t = threadIdx.x;
    for (int i = t; i < EMB * 16; i += 256) sW1[i] = Wh1[i];
    if (t < 16) { sbh1[t] = bh1[t]; sW2[t] = Wh2[t]; }
    if (t == 0) sbh2 = bh2[0];

    int l = t >> 2;                   // local node 0..63
    int q = t & 3;                    // channel quarter
    int node = blockIdx.x * 64 + l;

    if (node < N) {
        int r0 = row_off[node], r1 = row_off[node + 1];
        int deg = r1 - r0;

        __half2 a0 = __floats2half2_rn(0.f, 0.f), a1 = a0, a2 = a0, a3 = a0;
        int e = r0;
        for (; e + 2 <= r1; e += 2) {
            int i0 = csr[e], i1 = csr[e + 1];
            uint4 u0 = *(const uint4*)(p16 + (size_t)i0 * 16 + q * 4);
            uint4 u1 = *(const uint4*)(p16 + (size_t)i1 * 16 + q * 4);
            a0 = __hadd2(a0, u2h2(u0.x)); a1 = __hadd2(a1, u2h2(u0.y));
            a2 = __hadd2(a2, u2h2(u0.z)); a3 = __hadd2(a3, u2h2(u0.w));
            a0 = __hadd2(a0, u2h2(u1.x)); a1 = __hadd2(a1, u2h2(u1.y));
            a2 = __hadd2(a2, u2h2(u1.z)); a3 = __hadd2(a3, u2h2(u1.w));
        }
        if (e < r1) {
            uint4 u0 = *(const uint4*)(p16 + (size_t)csr[e] * 16 + q * 4);
            a0 = __hadd2(a0, u2h2(u0.x)); a1 = __hadd2(a1, u2h2(u0.y));
            a2 = __hadd2(a2, u2h2(u0.z)); a3 = __hadd2(a3, u2h2(u0.w));
        }

        float f[8];
        { float2 c = __half22float2(a0); f[0] = c.x; f[1] = c.y; }
        { float2 c = __half22float2(a1); f[2] = c.x; f[3] = c.y; }
        { float2 c = __half22float2(a2); f[4] = c.x; f[5] = c.y; }
        { float2 c = __half22float2(a3); f[6] = c.x; f[7] = c.y; }

        float inv = 1.0f / fmaxf((float)deg, 1.0f);
        const float4* sb = (const float4*)(selfb + (size_t)node * EMB + q * 8);
        float4 s0 = sb[0], s1 = sb[1];
        float* zrow = zs + l * 34 + q * 8;
        zrow[0] = fmaxf(f[0] * inv + s0.x, 0.0f);
        zrow[1] = fmaxf(f[1] * inv + s0.y, 0.0f);
        zrow[2] = fmaxf(f[2] * inv + s0.z, 0.0f);
        zrow[3] = fmaxf(f[3] * inv + s0.w, 0.0f);
        zrow[4] = fmaxf(f[4] * inv + s1.x, 0.0f);
        zrow[5] = fmaxf(f[5] * inv + s1.y, 0.0f);
        zrow[6] = fmaxf(f[6] * inv + s1.z, 0.0f);
        zrow[7] = fmaxf(f[7] * inv + s1.w, 0.0f);
    }
    __syncthreads();

    if (t < 64) {
        int node2 = blockIdx.x * 64 + t;
        if (node2 < N) {
            float zr[EMB];
            #pragma unroll
            for (int k = 0; k < EMB; k++) zr[k] = zs[t * 34 + k];
            float logit = sbh2;
            #pragma unroll
            for (int i = 0; i < 16; i++) {
                float acc = sbh1[i];
                #pragma unroll
                for (int k = 0; k < EMB; k++) acc += zr[k] * sW1[k * 16 + i];
                logit += fmaxf(acc, 0.0f) * sW2[i];
            }
            out[node2] = 1.0f / (1.0f + expf(-logit));
        }
    }
}

// ---------------------------------------------------------------- launch
extern "C" void kernel_launch(void* const* d_in, const int* in_sizes, int n_in,
                              void* d_out, int out_size, void* d_ws, size_t ws_size,
                              hipStream_t stream) {
    const float* x   = (const float*)d_in[0];
    const int*   ei  = (const int*)d_in[1];
    const float* W1l = (const float*)d_in[2];
    const float* b1  = (const float*)d_in[3];
    const float* W1r = (const float*)d_in[4];
    const float* W2l = (const float*)d_in[5];
    const float* b2  = (const float*)d_in[6];
    const float* W2r = (const float*)d_in[7];
    const float* Wh1 = (const float*)d_in[8];
    const float* bh1 = (const float*)d_in[9];
    const float* Wh2 = (const float*)d_in[10];
    const float* bh2 = (const float*)d_in[11];

    int N = in_sizes[0] / IN_CH;     // 100000
    int E = in_sizes[1] / 2;         // 3200000
    int NB = (N + BW - 1) / BW;      // 782 buckets
    int M  = NB * HBLK;              // histogram cells

    // workspace layout:
    // [staged int E][hist2 M][off2 M][tsum 4096][tpre 4096][row_off N+1][csr E]
    // [aggr 8N f32][selfb 32N f32][p16 16N u32]
    int* staged   = (int*)d_ws;
    int* hist2    = staged + E;
    int* off2     = hist2 + M;
    int* tsum     = off2 + M;
    int* tpre     = tsum + SCAN_T;
    int* row_off  = tpre + SCAN_T;
    int* csr      = row_off + (N + 1);
    float* aggr   = (float*)(csr + E);
    float* selfb  = aggr + (size_t)N * IN_CH;
    unsigned* p16 = (unsigned*)(selfb + (size_t)N * EMB);

    hist_kernel   <<<HBLK, 256, 0, stream>>>(ei, hist2, E, NB);
    hscanA_kernel <<<SCAN_T / 256, 256, 0, stream>>>(hist2, tsum, M, NB);
    hscanB_kernel <<<1, 256, 0, stream>>>(tsum, tpre);
    hscanC_kernel <<<SCAN_T / 256, 256, 0, stream>>>(hist2, tpre, off2, M, NB);
    scat_kernel   <<<HBLK, 256, 0, stream>>>(ei, off2, staged, E, NB);
    bucket_kernel <<<NB, 256, 0, stream>>>(staged, off2, row_off, csr, N, E, NB);
    gather1_kernel<<<(N + 63) / 64, 256, 0, stream>>>(x, row_off, csr, aggr, N);
    dense1b_kernel<<<(N + 127) / 128, 128, 0, stream>>>(x, aggr, W1l, b1, W1r,
                                                        W2l, b2, W2r, p16, selfb, N);
    gather2_kernel<<<(N + 63) / 64, 256, 0, stream>>>(p16, selfb, row_off, csr,
                                                      Wh1, bh1, Wh2, bh2, (float*)d_out, N);
}

// Round 9
// 202.923 us; speedup vs baseline: 4.7380x; 1.2139x over previous
//
#include <hip/hip_runtime.h>
#include <hip/hip_fp16.h>
#include <math.h>

#define IN_CH 8
#define HID   64
#define EMB   32
#define SCAN_T 4096     // 16 blocks x 256 for the histogram scan
#define HBLK  256       // blocks in hist/scatter phases
#define BW    256       // nodes per bucket (dst >> 8)
#define BSH   8         // log2(BW)
#define NBMAX 400       // max buckets supported (N <= 102400)
#define P8SCALE 128.0f

static __device__ __forceinline__ __half2 u2h2(unsigned u) {
    union { unsigned u; __half2 h; } c; c.u = u; return c.h;
}
static __device__ __forceinline__ unsigned h22u(__half2 h) {
    union { unsigned u; __half2 h; } c; c.h = h; return c.u;
}
static __device__ __forceinline__ void acc4(int* acc, unsigned u) {
    acc[0] += (int)(signed char)(u);
    acc[1] += (int)(signed char)(u >> 8);
    acc[2] += (int)(signed char)(u >> 16);
    acc[3] += (int)(signed char)(u >> 24);
}

// ------------------------------------------------- x -> fp16 rows (16B)
__global__ __launch_bounds__(256) void xh_kernel(const float* __restrict__ x,
                                                 unsigned* __restrict__ xh, int N) {
    int n = blockIdx.x * 256 + threadIdx.x;
    if (n >= N) return;
    float4 a = ((const float4*)(x + (size_t)n * IN_CH))[0];
    float4 b = ((const float4*)(x + (size_t)n * IN_CH))[1];
    uint4 o;
    o.x = h22u(__floats2half2_rn(a.x, a.y));
    o.y = h22u(__floats2half2_rn(a.z, a.w));
    o.z = h22u(__floats2half2_rn(b.x, b.y));
    o.w = h22u(__floats2half2_rn(b.z, b.w));
    ((uint4*)(xh + (size_t)n * 4))[0] = o;
}

// ------------------------------------------------- pass A1: per-block bucket histogram
__global__ __launch_bounds__(256) void hist_kernel(const int* __restrict__ ei,
                                                   int* __restrict__ hist2, int E, int NB) {
    __shared__ int lh[NBMAX];
    int b = blockIdx.x, t = threadIdx.x;
    for (int i = t; i < NB; i += 256) lh[i] = 0;
    __syncthreads();
    int per = (E + gridDim.x - 1) / gridDim.x;
    int e0 = b * per, e1 = min(e0 + per, E);
    for (int e = e0 + t; e < e1; e += 256)
        atomicAdd(&lh[ei[E + e] >> BSH], 1);
    __syncthreads();
    for (int i = t; i < NB; i += 256) hist2[b * NB + i] = lh[i];
}

// ------------------------------------------------- hist scan (bucket-major logical order)
// logical l = bucket*HBLK + block ; phys = block*NB + bucket
__global__ void hscanA_kernel(const int* __restrict__ hist2, int* __restrict__ tsum,
                              int M, int NB) {
    int tid = blockIdx.x * blockDim.x + threadIdx.x;
    int chunk = (M + SCAN_T - 1) / SCAN_T;
    int start = tid * chunk, end = min(start + chunk, M);
    int s = 0;
    for (int l = start; l < end; l++) s += hist2[(l & (HBLK - 1)) * NB + (l >> 8)];
    tsum[tid] = s;
}

__global__ __launch_bounds__(256) void hscanB_kernel(const int* __restrict__ tsum,
                                                     int* __restrict__ tpre) {
    __shared__ int bsum[256];
    int t = threadIdx.x;
    int s = 0;
    #pragma unroll
    for (int i = 0; i < 16; i++) s += tsum[t * 16 + i];
    bsum[t] = s;
    __syncthreads();
    for (int off = 1; off < 256; off <<= 1) {
        int v = (t >= off) ? bsum[t - off] : 0;
        __syncthreads();
        bsum[t] += v;
        __syncthreads();
    }
    int run = (t == 0) ? 0 : bsum[t - 1];
    #pragma unroll
    for (int i = 0; i < 16; i++) { tpre[t * 16 + i] = run; run += tsum[t * 16 + i]; }
}

__global__ void hscanC_kernel(const int* __restrict__ hist2, const int* __restrict__ tpre,
                              int* __restrict__ off2, int M, int NB) {
    int tid = blockIdx.x * blockDim.x + threadIdx.x;
    int chunk = (M + SCAN_T - 1) / SCAN_T;
    int start = tid * chunk, end = min(start + chunk, M);
    int run = tpre[tid];
    for (int l = start; l < end; l++) {
        int ph = (l & (HBLK - 1)) * NB + (l >> 8);
        off2[ph] = run;
        run += hist2[ph];
    }
}

// ------------------------------------------------- pass A2: scatter edges (packed src|li)
__global__ __launch_bounds__(256) void scat_kernel(const int* __restrict__ ei,
                                                   const int* __restrict__ off2,
                                                   int* __restrict__ staged, int E, int NB) {
    __shared__ int lcur[NBMAX];
    int b = blockIdx.x, t = threadIdx.x;
    for (int i = t; i < NB; i += 256) lcur[i] = off2[b * NB + i];
    __syncthreads();
    int per = (E + gridDim.x - 1) / gridDim.x;
    int e0 = b * per, e1 = min(e0 + per, E);
    for (int e = e0 + t; e < e1; e += 256) {
        int src = ei[e], dst = ei[E + e];
        int pos = atomicAdd(&lcur[dst >> BSH], 1);
        staged[pos] = src | ((dst & (BW - 1)) << 17);   // src<2^17, li<256
    }
}

// ------------------------------------------------- pass B: per-bucket CSR build
__global__ __launch_bounds__(256) void bucket_kernel(const int* __restrict__ staged,
                                                     const int* __restrict__ off2,
                                                     int* __restrict__ row_off,
                                                     int* __restrict__ csr,
                                                     int N, int E, int NB) {
    __shared__ int cnt[BW], offx[BW], cur[BW];
    int b = blockIdx.x, t = threadIdx.x;
    int base = b * BW;
    int s0 = off2[b];
    int s1 = (b + 1 < NB) ? off2[b + 1] : E;
    cnt[t] = 0;
    __syncthreads();
    for (int e = s0 + t; e < s1; e += 256)
        atomicAdd(&cnt[staged[e] >> 17], 1);
    __syncthreads();
    offx[t] = cnt[t];
    __syncthreads();
    for (int off = 1; off < BW; off <<= 1) {
        int v = (t >= off) ? offx[t - off] : 0;
        __syncthreads();
        offx[t] += v;
        __syncthreads();
    }
    {
        int ex = offx[t] - cnt[t];
        if (base + t < N) row_off[base + t] = s0 + ex;
        cnt[t] = ex;
        cur[t] = 0;
    }
    if (b == NB - 1 && t == 0) row_off[N] = s1;
    __syncthreads();
    for (int e = s0 + t; e < s1; e += 256) {
        int v = staged[e];
        int li = v >> 17;
        int pos = s0 + cnt[li] + atomicAdd(&cur[li], 1);
        csr[pos] = v & 0x1FFFF;
    }
}

// ------------------------------------------------- gather1: mean of fp16 x, 2 lanes/node
// lane q owns channels 4q..4q+3 (8B). 32 independent node streams per wave.
__global__ __launch_bounds__(256) void gather1_kernel(
        const unsigned* __restrict__ xh, const int* __restrict__ row_off,
        const int* __restrict__ csr, float* __restrict__ aggr, int N) {
    int t = threadIdx.x;
    int l = t >> 1, q = t & 1;
    int node = blockIdx.x * 128 + l;
    if (node >= N) return;
    int r0 = row_off[node], r1 = row_off[node + 1];
    int deg = r1 - r0;

    float a0 = 0.f, a1 = 0.f, a2 = 0.f, a3 = 0.f;
    int e = r0;
    for (; e + 4 <= r1; e += 4) {
        int i0 = csr[e], i1 = csr[e + 1], i2 = csr[e + 2], i3 = csr[e + 3];
        uint2 u0 = *(const uint2*)(xh + (size_t)i0 * 4 + q * 2);
        uint2 u1 = *(const uint2*)(xh + (size_t)i1 * 4 + q * 2);
        uint2 u2 = *(const uint2*)(xh + (size_t)i2 * 4 + q * 2);
        uint2 u3 = *(const uint2*)(xh + (size_t)i3 * 4 + q * 2);
        float2 f;
        f = __half22float2(u2h2(u0.x)); a0 += f.x; a1 += f.y;
        f = __half22float2(u2h2(u0.y)); a2 += f.x; a3 += f.y;
        f = __half22float2(u2h2(u1.x)); a0 += f.x; a1 += f.y;
        f = __half22float2(u2h2(u1.y)); a2 += f.x; a3 += f.y;
        f = __half22float2(u2h2(u2.x)); a0 += f.x; a1 += f.y;
        f = __half22float2(u2h2(u2.y)); a2 += f.x; a3 += f.y;
        f = __half22float2(u2h2(u3.x)); a0 += f.x; a1 += f.y;
        f = __half22float2(u2h2(u3.y)); a2 += f.x; a3 += f.y;
    }
    for (; e < r1; e++) {
        uint2 u0 = *(const uint2*)(xh + (size_t)csr[e] * 4 + q * 2);
        float2 f;
        f = __half22float2(u2h2(u0.x)); a0 += f.x; a1 += f.y;
        f = __half22float2(u2h2(u0.y)); a2 += f.x; a3 += f.y;
    }
    float inv = 1.0f / fmaxf((float)deg, 1.0f);
    ((float4*)(aggr + (size_t)node * IN_CH))[q] =
        make_float4(a0 * inv, a1 * inv, a2 * inv, a3 * inv);
}

// ------------------------------------------------- dense1b: node-per-thread dense chain
// h = relu(aggr@W1l + b1 + x@W1r); p8 = round(h@W2l * 128) int8 (32B row);
// self = h@W2r + b2 (fp32).
__global__ __launch_bounds__(128) void dense1b_kernel(
        const float* __restrict__ x, const float* __restrict__ aggr,
        const float* __restrict__ W1l, const float* __restrict__ b1,
        const float* __restrict__ W1r,
        const float* __restrict__ W2l, const float* __restrict__ b2,
        const float* __restrict__ W2r,
        unsigned* __restrict__ p8, float* __restrict__ selfb, int N) {
    int n = blockIdx.x * 128 + threadIdx.x;
    if (n >= N) return;

    float av[IN_CH], xv[IN_CH];
    {
        float4 a0 = ((const float4*)(aggr + (size_t)n * IN_CH))[0];
        float4 a1 = ((const float4*)(aggr + (size_t)n * IN_CH))[1];
        av[0] = a0.x; av[1] = a0.y; av[2] = a0.z; av[3] = a0.w;
        av[4] = a1.x; av[5] = a1.y; av[6] = a1.z; av[7] = a1.w;
        float4 b0 = ((const float4*)(x + (size_t)n * IN_CH))[0];
        float4 b1v = ((const float4*)(x + (size_t)n * IN_CH))[1];
        xv[0] = b0.x; xv[1] = b0.y; xv[2] = b0.z; xv[3] = b0.w;
        xv[4] = b1v.x; xv[5] = b1v.y; xv[6] = b1v.z; xv[7] = b1v.w;
    }

    float pacc[EMB], sacc[EMB];
    #pragma unroll
    for (int j = 0; j < EMB; j++) { pacc[j] = 0.0f; sacc[j] = b2[j]; }

    for (int k = 0; k < HID; k++) {
        float hk = b1[k];
        #pragma unroll
        for (int c = 0; c < IN_CH; c++)
            hk += av[c] * W1l[c * HID + k] + xv[c] * W1r[c * HID + k];
        hk = fmaxf(hk, 0.0f);
        const float* wl = W2l + k * EMB;
        const float* wr = W2r + k * EMB;
        #pragma unroll
        for (int j = 0; j < EMB; j++) {
            pacc[j] += hk * wl[j];
            sacc[j] += hk * wr[j];
        }
    }

    unsigned up[8];
    #pragma unroll
    for (int m = 0; m < 8; m++) {
        int q0 = min(127, max(-127, __float2int_rn(pacc[4 * m + 0] * P8SCALE)));
        int q1 = min(127, max(-127, __float2int_rn(pacc[4 * m + 1] * P8SCALE)));
        int q2 = min(127, max(-127, __float2int_rn(pacc[4 * m + 2] * P8SCALE)));
        int q3 = min(127, max(-127, __float2int_rn(pacc[4 * m + 3] * P8SCALE)));
        up[m] = (unsigned)(q0 & 255) | ((unsigned)(q1 & 255) << 8)
              | ((unsigned)(q2 & 255) << 16) | ((unsigned)(q3 & 255) << 24);
    }
    uint4* pp = (uint4*)(p8 + (size_t)n * 8);
    pp[0] = make_uint4(up[0], up[1], up[2], up[3]);
    pp[1] = make_uint4(up[4], up[5], up[6], up[7]);
    float4* sp = (float4*)(selfb + (size_t)n * EMB);
    #pragma unroll
    for (int m = 0; m < 8; m++)
        sp[m] = make_float4(sacc[4 * m], sacc[4 * m + 1], sacc[4 * m + 2], sacc[4 * m + 3]);
}

// ------------------------------------------------- gather2: 2 lanes/node int8 + head
// lane q owns channels 16q..16q+15 (one uint4 of the 32B int8 p-row). Exact
// int32 accumulate, 32 node streams/wave, unroll 4. Phase 2: thread-per-node
// head MLP through padded LDS.
__global__ __launch_bounds__(256) void gather2_kernel(
        const unsigned* __restrict__ p8, const float* __restrict__ selfb,
        const int* __restrict__ row_off, const int* __restrict__ csr,
        const float* __restrict__ Wh1, const float* __restrict__ bh1,
        const float* __restrict__ Wh2, const float* __restrict__ bh2,
        float* __restrict__ out, int N) {
    __shared__ float zs[128 * 34];    // pitch 34: 2-way max conflicts (free)
    __shared__ float sW1[EMB * 16];
    __shared__ float sbh1[16];
    __shared__ float sW2[16];
    __shared__ float sbh2;
    int t = threadIdx.x;
    for (int i = t; i < EMB * 16; i += 256) sW1[i] = Wh1[i];
    if (t < 16) { sbh1[t] = bh1[t]; sW2[t] = Wh2[t]; }
    if (t == 0) sbh2 = bh2[0];

    int l = t >> 1, q = t & 1;
    int node = blockIdx.x * 128 + l;

    if (node < N) {
        int r0 = row_off[node], r1 = row_off[node + 1];
        int deg = r1 - r0;

        int acc[16];
        #pragma unroll
        for (int j = 0; j < 16; j++) acc[j] = 0;

        int e = r0;
        for (; e + 4 <= r1; e += 4) {
            int i0 = csr[e], i1 = csr[e + 1], i2 = csr[e + 2], i3 = csr[e + 3];
            uint4 u0 = *(const uint4*)(p8 + (size_t)i0 * 8 + q * 4);
            uint4 u1 = *(const uint4*)(p8 + (size_t)i1 * 8 + q * 4);
            uint4 u2 = *(const uint4*)(p8 + (size_t)i2 * 8 + q * 4);
            uint4 u3 = *(const uint4*)(p8 + (size_t)i3 * 8 + q * 4);
            acc4(acc + 0, u0.x); acc4(acc + 4, u0.y); acc4(acc + 8, u0.z); acc4(acc + 12, u0.w);
            acc4(acc + 0, u1.x); acc4(acc + 4, u1.y); acc4(acc + 8, u1.z); acc4(acc + 12, u1.w);
            acc4(acc + 0, u2.x); acc4(acc + 4, u2.y); acc4(acc + 8, u2.z); acc4(acc + 12, u2.w);
            acc4(acc + 0, u3.x); acc4(acc + 4, u3.y); acc4(acc + 8, u3.z); acc4(acc + 12, u3.w);
        }
        for (; e < r1; e++) {
            uint4 u0 = *(const uint4*)(p8 + (size_t)csr[e] * 8 + q * 4);
            acc4(acc + 0, u0.x); acc4(acc + 4, u0.y); acc4(acc + 8, u0.z); acc4(acc + 12, u0.w);
        }

        float s = (1.0f / P8SCALE) / fmaxf((float)deg, 1.0f);
        const float4* sb = (const float4*)(selfb + (size_t)node * EMB + q * 16);
        float* zrow = zs + l * 34 + q * 16;
        #pragma unroll
        for (int m = 0; m < 4; m++) {
            float4 s4 = sb[m];
            zrow[4 * m + 0] = fmaxf((float)acc[4 * m + 0] * s + s4.x, 0.0f);
            zrow[4 * m + 1] = fmaxf((float)acc[4 * m + 1] * s + s4.y, 0.0f);
            zrow[4 * m + 2] = fmaxf((float)acc[4 * m + 2] * s + s4.z, 0.0f);
            zrow[4 * m + 3] = fmaxf((float)acc[4 * m + 3] * s + s4.w, 0.0f);
        }
    }
    __syncthreads();

    if (t < 128) {
        int node2 = blockIdx.x * 128 + t;
        if (node2 < N) {
            float zr[EMB];
            #pragma unroll
            for (int k = 0; k < EMB; k++) zr[k] = zs[t * 34 + k];
            float logit = sbh2;
            #pragma unroll
            for (int i = 0; i < 16; i++) {
                float acc = sbh1[i];
                #pragma unroll
                for (int k = 0; k < EMB; k++) acc += zr[k] * sW1[k * 16 + i];
                logit += fmaxf(acc, 0.0f) * sW2[i];
            }
            out[node2] = 1.0f / (1.0f + expf(-logit));
        }
    }
}

// ---------------------------------------------------------------- launch
extern "C" void kernel_launch(void* const* d_in, const int* in_sizes, int n_in,
                              void* d_out, int out_size, void* d_ws, size_t ws_size,
                              hipStream_t stream) {
    const float* x   = (const float*)d_in[0];
    const int*   ei  = (const int*)d_in[1];
    const float* W1l = (const float*)d_in[2];
    const float* b1  = (const float*)d_in[3];
    const float* W1r = (const float*)d_in[4];
    const float* W2l = (const float*)d_in[5];
    const float* b2  = (const float*)d_in[6];
    const float* W2r = (const float*)d_in[7];
    const float* Wh1 = (const float*)d_in[8];
    const float* bh1 = (const float*)d_in[9];
    const float* Wh2 = (const float*)d_in[10];
    const float* bh2 = (const float*)d_in[11];

    int N = in_sizes[0] / IN_CH;     // 100000
    int E = in_sizes[1] / 2;         // 3200000
    int NB = (N + BW - 1) / BW;      // 391 buckets
    int M  = NB * HBLK;              // histogram cells

    // workspace layout:
    // [staged int E][hist2 M][off2 M][tsum 4096][tpre 4096][row_off N+1][csr E]
    // [xh 4N u32][aggr 8N f32][selfb 32N f32][p8 8N u32]
    int* staged   = (int*)d_ws;
    int* hist2    = staged + E;
    int* off2     = hist2 + M;
    int* tsum     = off2 + M;
    int* tpre     = tsum + SCAN_T;
    int* row_off  = tpre + SCAN_T;
    int* csr      = row_off + (N + 1);
    unsigned* xh  = (unsigned*)(csr + E);
    float* aggr   = (float*)(xh + (size_t)N * 4);
    float* selfb  = aggr + (size_t)N * IN_CH;
    unsigned* p8  = (unsigned*)(selfb + (size_t)N * EMB);

    xh_kernel     <<<(N + 255) / 256, 256, 0, stream>>>(x, xh, N);
    hist_kernel   <<<HBLK, 256, 0, stream>>>(ei, hist2, E, NB);
    hscanA_kernel <<<SCAN_T / 256, 256, 0, stream>>>(hist2, tsum, M, NB);
    hscanB_kernel <<<1, 256, 0, stream>>>(tsum, tpre);
    hscanC_kernel <<<SCAN_T / 256, 256, 0, stream>>>(hist2, tpre, off2, M, NB);
    scat_kernel   <<<HBLK, 256, 0, stream>>>(ei, off2, staged, E, NB);
    bucket_kernel <<<NB, 256, 0, stream>>>(staged, off2, row_off, csr, N, E, NB);
    gather1_kernel<<<(N + 127) / 128, 256, 0, stream>>>(xh, row_off, csr, aggr, N);
    dense1b_kernel<<<(N + 127) / 128, 128, 0, stream>>>(x, aggr, W1l, b1, W1r,
                                                        W2l, b2, W2r, p8, selfb, N);
    gather2_kernel<<<(N + 127) / 128, 256, 0, stream>>>(p8, selfb, row_off, csr,
                                                        Wh1, bh1, Wh2, bh2, (float*)d_out, N);
}